// Round 8
// baseline (209.219 us; speedup 1.0000x reference)
//
#include <hip/hip_runtime.h>

// x: [B=64, C=2048, J=8] fp32 ; W: [K=32, C=2048, I=16, J=8] fp32
// out v: [B=64, K=32, I=16] fp32
#define Bn 64
#define Cn 2048
#define Kn 32
#define In 16
#define EPSf 1e-7f

#define NOUT (Bn * Kn * In)   // 32768
#define KJ   (Cn * 8)         // 16384 contraction length
#define KSPL 64               // split-K for both GEMMs

typedef short bf8v __attribute__((ext_vector_type(8)));
typedef float f4v  __attribute__((ext_vector_type(4)));
typedef float v2f  __attribute__((ext_vector_type(2)));

union U16B { uint4 u; bf8v v; unsigned short h[8]; };

__device__ __forceinline__ unsigned short f2bf(float f) {
    unsigned u = __float_as_uint(f);
    u += 0x7FFF + ((u >> 16) & 1);          // RNE
    return (unsigned short)(u >> 16);
}

__device__ __forceinline__ bf8v cvt8(float4 a, float4 b) {
    U16B o;
    o.h[0] = f2bf(a.x); o.h[1] = f2bf(a.y); o.h[2] = f2bf(a.z); o.h[3] = f2bf(a.w);
    o.h[4] = f2bf(b.x); o.h[5] = f2bf(b.y); o.h[6] = f2bf(b.z); o.h[7] = f2bf(b.w);
    return o.v;
}

__device__ __forceinline__ float dot8v(float4 wA, float4 wB, float4 xA, float4 xB) {
    union F2 { float4 f; v2f h[2]; };
    F2 ua{wA}, ub{wB}, xa{xA}, xb{xB};
    v2f s = ua.h[0] * xa.h[0];
    s += ua.h[1] * xa.h[1];
    s += ub.h[0] * xb.h[0];
    s += ub.h[1] * xb.h[1];
    return s.x + s.y;
}

// ---------------------------------------------------------------------------
// kGemm1: iter-1 S1 partials via MFMA (B-frag map validated R5-R7).
// 512 blocks = 8 nstrips x 64 ksplits; 4 waves = 4 m-tiles (all of B).
// ---------------------------------------------------------------------------
__global__ __launch_bounds__(256) void kGemm1(const float* __restrict__ x,
                                              const float* __restrict__ W,
                                              float* __restrict__ part1)
{
    const int nstrip = blockIdx.x & 7;
    const int ksplit = blockIdx.x >> 3;       // 0..63
    const int ks0    = ksplit * (512 / KSPL);
    const int lane   = threadIdx.x & 63;
    const int m0     = (threadIdx.x >> 6) * 16;

    f4v acc[4] = {};
    const float* xrow = x + (size_t)(m0 + (lane & 15)) * KJ + (lane >> 4) * 8;

    #pragma unroll
    for (int s = 0; s < 512 / KSPL; ++s) {
        const int ks = ks0 + s;
        const float4* xp = (const float4*)(xrow + ks * 32);
        bf8v af = cvt8(xp[0], xp[1]);
        #pragma unroll
        for (int t = 0; t < 4; ++t) {
            const int nt = nstrip * 4 + t;            // == k_out
            const int c  = ks * 4 + (lane >> 4);
            const float4* wp = (const float4*)(W + (((size_t)nt * Cn + c) * 16 + (lane & 15)) * 8);
            bf8v bfr = cvt8(wp[0], wp[1]);
            acc[t] = __builtin_amdgcn_mfma_f32_16x16x32_bf16(af, bfr, acc[t], 0, 0, 0);
        }
    }

    float* pb = part1 + (size_t)ksplit * NOUT;
    const int col   = lane & 15;
    const int rbase = (lane >> 4) * 4;
    #pragma unroll
    for (int t = 0; t < 4; ++t) {
        const int n = (nstrip * 4 + t) * 16 + col;
        #pragma unroll
        for (int r = 0; r < 4; ++r)
            pb[(size_t)(m0 + rbase + r) * 512 + n] = acc[t][r];
    }
}

// ---------------------------------------------------------------------------
// kSqT: out[t] = squash_i( scale * sum_g part[g][t] ).  Thread per element:
// 32768 threads = 128 blocks; loads coalesced per g; i-norm = 4 xor shuffles.
// ---------------------------------------------------------------------------
template <int NP>
__global__ __launch_bounds__(256) void kSqT(const float* __restrict__ part,
                                            float* __restrict__ out, float scale)
{
    const int t = blockIdx.x * 256 + threadIdx.x;   // 0..32767
    float s = 0.0f;
    #pragma unroll
    for (int g = 0; g < NP; ++g) s += part[(size_t)g * NOUT + t];
    s *= scale;
    float sq = s * s;
    sq += __shfl_xor(sq, 1);
    sq += __shfl_xor(sq, 2);
    sq += __shfl_xor(sq, 4);
    sq += __shfl_xor(sq, 8);
    const float f = (sq / (1.0f + sq)) * rsqrtf(sq + EPSf);
    out[t] = s * f;
}

// ---------------------------------------------------------------------------
// kAgr: agreements + softmax -> cc[k][c][b].  Thread = (k, cl): owns ONE c
// per chunk and ALL 16 i -> agreement is pure register FMA, no shuffles.
// BSUB=4 b per block reuse W loads. e_s[4][8][40]: banks (8*cl+k)%32, max
// 2-way = free.  XCD swizzle: xcd owns a 16-cg band, bg fastest. 2048 blocks.
// ---------------------------------------------------------------------------
__global__ __launch_bounds__(256) void kAgr(const float* __restrict__ x,
                                            const float* __restrict__ W,
                                            const float* __restrict__ v1,
                                            float* __restrict__ cc)
{
    const int xcd = blockIdx.x & 7;
    const int idx = blockIdx.x >> 3;          // 0..255
    const int bg  = idx & 15;                 // fastest: 16 bgroups
    const int cgl = idx >> 4;                 // 0..15
    const int cg  = xcd * 16 + cgl;           // 0..127
    const int k   = threadIdx.x >> 3;         // 0..31
    const int cl  = threadIdx.x & 7;          // 0..7

    __shared__ float e_s[4][8][40];
    __shared__ float dinv[32];

    float v1r[4][16];
    #pragma unroll
    for (int b = 0; b < 4; ++b) {
        const float* vp = v1 + ((size_t)((bg * 4 + b) * Kn + k)) * In;
        #pragma unroll
        for (int q = 0; q < 4; ++q) {
            const float4 v = *(const float4*)(vp + q * 4);
            v1r[b][q * 4 + 0] = v.x; v1r[b][q * 4 + 1] = v.y;
            v1r[b][q * 4 + 2] = v.z; v1r[b][q * 4 + 3] = v.w;
        }
    }

    for (int ch = 0; ch < 2; ++ch) {
        const int c = cg * 16 + ch * 8 + cl;

        float4 xr[4][2];
        #pragma unroll
        for (int b = 0; b < 4; ++b) {
            const float4* xp = (const float4*)(x + ((size_t)((bg * 4 + b) * Cn + c)) * 8);
            xr[b][0] = xp[0];
            xr[b][1] = xp[1];
        }

        float agr[4] = {};
        const float4* wp = (const float4*)(W + ((size_t)(k * Cn + c)) * 128);
        #pragma unroll
        for (int i = 0; i < 16; ++i) {
            float4 w0 = wp[2 * i], w1 = wp[2 * i + 1];
            #pragma unroll
            for (int b = 0; b < 4; ++b) {
                const float d = dot8v(w0, w1, xr[b][0], xr[b][1]);
                agr[b] += d * v1r[b][i];
            }
        }
        #pragma unroll
        for (int b = 0; b < 4; ++b) e_s[b][cl][k] = __expf(agr[b]);
        __syncthreads();

        // ---- softmax denominators: 32 (b,cl) pairs x 8 lanes ----
        {
            const int p  = threadIdx.x >> 3;   // 0..31
            const int l  = threadIdx.x & 7;
            const int pb = p >> 3, pc = p & 7;
            const float* ep = &e_s[pb][pc][4 * l];
            float ssum = (ep[0] + ep[1]) + (ep[2] + ep[3]);
            ssum += __shfl_xor(ssum, 1);
            ssum += __shfl_xor(ssum, 2);
            ssum += __shfl_xor(ssum, 4);
            if (l == 0) dinv[p] = 1.0f / ssum;
        }
        __syncthreads();

        // ---- write cc[k][c][b0..b3] as one float4 ----
        {
            float4 o;
            o.x = e_s[0][cl][k] * dinv[0 * 8 + cl];
            o.y = e_s[1][cl][k] * dinv[1 * 8 + cl];
            o.z = e_s[2][cl][k] * dinv[2 * 8 + cl];
            o.w = e_s[3][cl][k] * dinv[3 * 8 + cl];
            *(float4*)(cc + ((size_t)k * Cn + c) * Bn + bg * 4) = o;
        }
        __syncthreads();   // e_s overwritten next chunk
    }
}

// ---------------------------------------------------------------------------
// kGemm2: s2 partials via MFMA, cc folded into A.  4 kk per wave -> 4
// independent MFMA chains, x-load shared across kk.  512 blocks = 8 kkg x
// 64 ksplits; 4 waves = 4 m-tiles of 16 b.
// ---------------------------------------------------------------------------
__global__ __launch_bounds__(256) void kGemm2(const float* __restrict__ x,
                                              const float* __restrict__ W,
                                              const float* __restrict__ cc,
                                              float* __restrict__ part2)
{
    const int kkg = blockIdx.x & 7;           // 4 kk each
    const int ksp = blockIdx.x >> 3;          // 0..63
    const int lane = threadIdx.x & 63;
    const int m0   = (threadIdx.x >> 6) * 16;
    const int b    = m0 + (lane & 15);

    f4v acc[4] = {};

    #pragma unroll
    for (int s = 0; s < 512 / KSPL; ++s) {
        const int kstep = ksp * (512 / KSPL) + s;
        const int c = kstep * 4 + (lane >> 4);
        const float4* xp = (const float4*)(x + ((size_t)b * Cn + c) * 8);
        const float4 x0 = xp[0], x1 = xp[1];
        #pragma unroll
        for (int t = 0; t < 4; ++t) {
            const int kk = kkg * 4 + t;
            const float ccv = cc[((size_t)kk * Cn + c) * Bn + b];
            float4 a0 = x0, a1 = x1;
            a0.x *= ccv; a0.y *= ccv; a0.z *= ccv; a0.w *= ccv;
            a1.x *= ccv; a1.y *= ccv; a1.z *= ccv; a1.w *= ccv;
            bf8v af = cvt8(a0, a1);
            const float4* wp = (const float4*)(W + (((size_t)kk * Cn + c) * 16 + (lane & 15)) * 8);
            bf8v bfr = cvt8(wp[0], wp[1]);
            acc[t] = __builtin_amdgcn_mfma_f32_16x16x32_bf16(af, bfr, acc[t], 0, 0, 0);
        }
    }

    // C/D: col = lane&15 = i, row = b
    float* pb = part2 + (size_t)ksp * NOUT;
    const int i     = lane & 15;
    const int rbase = m0 + (lane >> 4) * 4;
    #pragma unroll
    for (int t = 0; t < 4; ++t) {
        const int kk = kkg * 4 + t;
        #pragma unroll
        for (int r = 0; r < 4; ++r)
            pb[((size_t)(rbase + r) * Kn + kk) * In + i] = acc[t][r];
    }
}

extern "C" void kernel_launch(void* const* d_in, const int* in_sizes, int n_in,
                              void* d_out, int out_size, void* d_ws, size_t ws_size,
                              hipStream_t stream)
{
    const float* x = (const float*)d_in[0];   // [64,2048,8]
    const float* W = (const float*)d_in[1];   // [32,2048,16,8]
    float* out = (float*)d_out;               // [64,32,16]

    // ws: partS (8 MiB, shared by iter-1 and iter-2 partials: kSqT fully
    // consumes it before kGemm2 rewrites — stream-ordered), v1, cc.
    float* wsf   = (float*)d_ws;
    float* partS = wsf;                                   // 64*32768 = 8 MiB
    float* v1    = wsf + (size_t)KSPL * NOUT;             // 128 KiB
    float* cc    = v1 + NOUT;                             // 32*2048*64 = 16.8 MiB

    kGemm1<<<512,  256, 0, stream>>>(x, W, partS);
    kSqT<KSPL><<<128, 256, 0, stream>>>(partS, v1, 1.0f / 32.0f);
    kAgr  <<<2048, 256, 0, stream>>>(x, W, v1, cc);
    kGemm2<<<512,  256, 0, stream>>>(x, W, cc, partS);
    kSqT<KSPL><<<128, 256, 0, stream>>>(partS, out, 1.0f);
}